// Round 1
// baseline (261.975 us; speedup 1.0000x reference)
//
#include <hip/hip_runtime.h>
#include <hip/hip_bf16.h>

// Problem constants
#define D    128
#define NQ   2048
#define NP   256
#define H1   128
#define H2   64
#define QR   8     // rows per proj block
#define QB   8     // q-rows per main block

// ---------------------------------------------------------------------------
// Workspace layout (floats):
//   qhb   [NQ][H1]      q @ W1q^T + b1                     off 0       (262144)
//   pht   [H1][NP]      (p @ W1p^T)^T                      off 262144  (32768)
//   w1qt  [D][H1]       W1[:, :D]^T                        off 294912  (16384)
//   w1pt  [D][H1]       W1[:, D:]^T                        off 311296  (16384)
//   w2t   [H1][H2]      W2^T                               off 327680  (8192)
//   qn    [NQ]                                              off 335872  (2048)
//   pn    [NP]                                              off 337920  (256)
//   base  [NQ][NP]      max(qn+pn-2*q@p^T, 0)              off 338176  (524288)
// ---------------------------------------------------------------------------
#define OFF_QHB   0
#define OFF_PHT   262144
#define OFF_W1QT  294912
#define OFF_W1PT  311296
#define OFF_W2T   327680
#define OFF_QN    335872
#define OFF_PN    337920
#define OFF_BASE  338176

// Transpose W1 (q and p halves) and W2. grid 192 x 256
__global__ void transpose_kernel(const float* __restrict__ W1,
                                 const float* __restrict__ W2,
                                 float* __restrict__ w1qt,
                                 float* __restrict__ w1pt,
                                 float* __restrict__ w2t) {
    int b = blockIdx.x, c = threadIdx.x;
    if (b < H1) {
        float v = W1[b * (2 * D) + c];
        if (c < D) w1qt[c * H1 + b] = v;
        else       w1pt[(c - D) * H1 + b] = v;
    } else {
        int o = b - H1;           // 0..63
        if (c < H1) w2t[c * H2 + o] = W2[o * H1 + c];
    }
}

// Projection: out = X @ W1part^T (+bias). w1t is [d][o] (128x128).
// Block: 256 threads = 128 outputs x 2 K-halves (lane pairs), QR rows/block.
__global__ void proj_kernel(const float* __restrict__ X,
                            const float* __restrict__ w1t,
                            const float* __restrict__ bias,
                            float* __restrict__ outMat,
                            float* __restrict__ norms,
                            int transposedStore) {
    __shared__ float w1s[D * H1];   // 64 KB, [d][o]
    int tid = threadIdx.x;
    // stage w1t (linear, coalesced)
    const float4* s4 = (const float4*)w1t;
    float4* d4 = (float4*)w1s;
    #pragma unroll
    for (int i = tid; i < (D * H1) / 4; i += 256) d4[i] = s4[i];
    __syncthreads();

    int o  = tid >> 1;     // 0..127
    int kh = tid & 1;      // K half
    int r0 = blockIdx.x * QR;
    float bv = (bias != nullptr) ? bias[o] : 0.f;

    for (int r = 0; r < QR; ++r) {
        const float* xrow = X + (r0 + r) * D + kh * 64;
        const float* wcol = w1s + kh * 64 * H1 + o;
        float acc = 0.f;
        #pragma unroll 8
        for (int i = 0; i < 64; ++i)
            acc = fmaf(xrow[i], wcol[i * H1], acc);
        acc += __shfl_xor(acc, 1);
        if (kh == 0) {
            float v = acc + bv;
            if (transposedStore) outMat[o * NP + (r0 + r)] = v;
            else                 outMat[(r0 + r) * H1 + o] = v;
        }
    }
    // row norms
    if (tid < QR) {
        const float* xr = X + (r0 + tid) * D;
        float s = 0.f;
        for (int d = 0; d < D; ++d) s = fmaf(xr[d], xr[d], s);
        norms[r0 + tid] = s;
    }
}

// base[q][p] = max(qn+pn-2*q.p, 0). Tile 32q x 64p, 256 threads, grid 64*4.
#define BQ 32
#define BP 64
__global__ void base_kernel(const float* __restrict__ Q,
                            const float* __restrict__ P,
                            const float* __restrict__ qn,
                            const float* __restrict__ pn,
                            float* __restrict__ baseOut) {
    __shared__ float q_s[BQ][D + 1];
    __shared__ float p_s[BP][D + 1];
    int bq = blockIdx.x >> 2;         // 0..63
    int bp = blockIdx.x & 3;          // 0..3
    int q0 = bq * BQ, p0 = bp * BP;
    int tid = threadIdx.x;

    for (int i = tid; i < BQ * D; i += 256)
        q_s[i >> 7][i & 127] = Q[(q0 + (i >> 7)) * D + (i & 127)];
    for (int i = tid; i < BP * D; i += 256)
        p_s[i >> 7][i & 127] = P[(p0 + (i >> 7)) * D + (i & 127)];
    __syncthreads();

    int tp = tid & 15, tq = tid >> 4;     // tq 0..15
    int rq = tq * 2, cp = tp * 4;
    float acc[2][4] = {{0.f, 0.f, 0.f, 0.f}, {0.f, 0.f, 0.f, 0.f}};
    for (int d = 0; d < D; ++d) {
        float qa0 = q_s[rq][d],   qa1 = q_s[rq + 1][d];
        float pb0 = p_s[cp][d],   pb1 = p_s[cp + 1][d];
        float pb2 = p_s[cp + 2][d], pb3 = p_s[cp + 3][d];
        acc[0][0] = fmaf(qa0, pb0, acc[0][0]);
        acc[0][1] = fmaf(qa0, pb1, acc[0][1]);
        acc[0][2] = fmaf(qa0, pb2, acc[0][2]);
        acc[0][3] = fmaf(qa0, pb3, acc[0][3]);
        acc[1][0] = fmaf(qa1, pb0, acc[1][0]);
        acc[1][1] = fmaf(qa1, pb1, acc[1][1]);
        acc[1][2] = fmaf(qa1, pb2, acc[1][2]);
        acc[1][3] = fmaf(qa1, pb3, acc[1][3]);
    }
    #pragma unroll
    for (int j = 0; j < 2; ++j) {
        float qv = qn[q0 + rq + j];
        float4 v;
        v.x = fmaxf(qv + pn[p0 + cp + 0] - 2.f * acc[j][0], 0.f);
        v.y = fmaxf(qv + pn[p0 + cp + 1] - 2.f * acc[j][1], 0.f);
        v.z = fmaxf(qv + pn[p0 + cp + 2] - 2.f * acc[j][2], 0.f);
        v.w = fmaxf(qv + pn[p0 + cp + 3] - 2.f * acc[j][3], 0.f);
        *(float4*)(baseOut + (q0 + rq + j) * NP + p0 + cp) = v;
    }
}

// Main: per (q,p) pair the MLP. Block = 256 threads = 256 p values, QB q rows.
// ph^T staged in 128 KB dynamic LDS. W2^T rows read at uniform addresses.
__global__ void __launch_bounds__(256, 1)
main_kernel(const float* __restrict__ qhb,
            const float* __restrict__ pht,
            const float* __restrict__ w2t,
            const float* __restrict__ b2,
            const float* __restrict__ w3,
            const float* __restrict__ b3,
            const float* __restrict__ baseM,
            float* __restrict__ out) {
    extern __shared__ float pht_s[];   // [H1][NP] = 32768 floats
    int tid = threadIdx.x;
    int q0 = blockIdx.x * QB;

    const float4* src4 = (const float4*)pht;
    float4* dst4 = (float4*)pht_s;
    #pragma unroll
    for (int i = tid; i < (H1 * NP) / 4; i += 256) dst4[i] = src4[i];
    __syncthreads();

    int p = tid;
    float b3v = b3[0];

    for (int q = 0; q < QB; ++q) {
        const float* qrow = qhb + (q0 + q) * H1;
        float acc[H2];
        #pragma unroll
        for (int o = 0; o < H2; ++o) acc[o] = 0.f;

        #pragma unroll 2
        for (int h = 0; h < H1; ++h) {
            float a  = qrow[h];                         // uniform -> s_load
            float h1 = fmaxf(a + pht_s[h * NP + p], 0.f);
            const float4* w2r = (const float4*)(w2t + h * H2);   // uniform
            #pragma unroll
            for (int j = 0; j < H2 / 4; ++j) {
                float4 w = w2r[j];
                acc[4 * j + 0] = fmaf(h1, w.x, acc[4 * j + 0]);
                acc[4 * j + 1] = fmaf(h1, w.y, acc[4 * j + 1]);
                acc[4 * j + 2] = fmaf(h1, w.z, acc[4 * j + 2]);
                acc[4 * j + 3] = fmaf(h1, w.w, acc[4 * j + 3]);
            }
        }

        // epilogue: h2 = relu(acc+b2); z = h2.w3 + b3; softplus; weight
        float s0 = 0.f, s1 = 0.f, s2 = 0.f, s3 = 0.f;
        #pragma unroll
        for (int o = 0; o < H2; o += 4) {
            s0 = fmaf(fmaxf(acc[o + 0] + b2[o + 0], 0.f), w3[o + 0], s0);
            s1 = fmaf(fmaxf(acc[o + 1] + b2[o + 1], 0.f), w3[o + 1], s1);
            s2 = fmaf(fmaxf(acc[o + 2] + b2[o + 2], 0.f), w3[o + 2], s2);
            s3 = fmaf(fmaxf(acc[o + 3] + b2[o + 3], 0.f), w3[o + 3], s3);
        }
        float z  = (s0 + s1) + (s2 + s3) + b3v;
        float sp = fmaxf(z, 0.f) + log1pf(expf(-fabsf(z)));   // stable softplus
        float alpha = 1.f + sp;
        float cw = 1.f / (1.f / alpha + 1e-8f);
        int idx = (q0 + q) * NP + p;
        out[idx] = baseM[idx] * cw;
    }
}

extern "C" void kernel_launch(void* const* d_in, const int* in_sizes, int n_in,
                              void* d_out, int out_size, void* d_ws, size_t ws_size,
                              hipStream_t stream) {
    const float* q  = (const float*)d_in[0];
    const float* pr = (const float*)d_in[1];
    const float* W1 = (const float*)d_in[2];
    const float* b1 = (const float*)d_in[3];
    const float* W2 = (const float*)d_in[4];
    const float* b2 = (const float*)d_in[5];
    const float* W3 = (const float*)d_in[6];
    const float* b3 = (const float*)d_in[7];
    float* out = (float*)d_out;
    float* ws  = (float*)d_ws;

    float* qhb  = ws + OFF_QHB;
    float* pht  = ws + OFF_PHT;
    float* w1qt = ws + OFF_W1QT;
    float* w1pt = ws + OFF_W1PT;
    float* w2t  = ws + OFF_W2T;
    float* qn   = ws + OFF_QN;
    float* pn   = ws + OFF_PN;
    float* baseM = ws + OFF_BASE;

    transpose_kernel<<<H1 + H2, 256, 0, stream>>>(W1, W2, w1qt, w1pt, w2t);

    proj_kernel<<<NQ / QR, 256, 0, stream>>>(q, w1qt, b1, qhb, qn, 0);
    proj_kernel<<<NP / QR, 256, 0, stream>>>(pr, w1pt, nullptr, pht, pn, 1);

    base_kernel<<<(NQ / BQ) * (NP / BP), 256, 0, stream>>>(q, pr, qn, pn, baseM);

    main_kernel<<<NQ / QB, 256, H1 * NP * (int)sizeof(float), stream>>>(
        qhb, pht, w2t, b2, W3, b3, baseM, out);
}

// Round 2
// 92.357 us; speedup vs baseline: 2.8366x; 2.8366x over previous
//
#include <hip/hip_runtime.h>
#include <hip/hip_bf16.h>

// Problem constants
#define D    128
#define NQ   2048
#define NP   256
#define H1   128
#define H2   64
#define QR   8     // rows per proj block
#define QB   4     // q-rows per main block

typedef __attribute__((ext_vector_type(8))) short short8;
typedef __attribute__((ext_vector_type(4))) float f32x4;

// ---------------------------------------------------------------------------
// Workspace layout (float units):
//   qhb   [NQ][H1]  f32   q @ W1q^T + b1            off 0       (262144)
//   phb   [NP][H1]  bf16  p @ W1p^T                 off 262144  (16384 f32 slots)
//   w1qt  [D][H1]   f32   W1[:, :D]^T               off 278528  (16384)
//   w1pt  [D][H1]   f32   W1[:, D:]^T               off 294912  (16384)
//   qn    [NQ]                                       off 311296  (2048)
//   pn    [NP]                                       off 313344  (256)
//   base  [NQ][NP]  f32                              off 313600  (524288)
// ---------------------------------------------------------------------------
#define OFF_QHB   0
#define OFF_PHB   262144
#define OFF_W1QT  278528
#define OFF_W1PT  294912
#define OFF_QN    311296
#define OFF_PN    313344
#define OFF_BASE  313600

static __device__ __forceinline__ short f2bf(float x) {
    __bf16 h = (__bf16)x;                 // RNE convert (compiler emits v_cvt)
    union { __bf16 b; short s; } u; u.b = h;
    return u.s;
}
static __device__ __forceinline__ float bflo(unsigned u) {
    union { unsigned u; float f; } v; v.u = u << 16; return v.f;
}
static __device__ __forceinline__ float bfhi(unsigned u) {
    union { unsigned u; float f; } v; v.u = u & 0xFFFF0000u; return v.f;
}

// Transpose W1 halves. grid H1 x 256
__global__ void transpose_kernel(const float* __restrict__ W1,
                                 float* __restrict__ w1qt,
                                 float* __restrict__ w1pt) {
    int b = blockIdx.x, c = threadIdx.x;
    float v = W1[b * (2 * D) + c];
    if (c < D) w1qt[c * H1 + b] = v;
    else       w1pt[(c - D) * H1 + b] = v;
}

// Projection: out = X @ W1part^T (+bias). w1t is [d][o] (128x128).
// f32 output (q path) or bf16 output (p path), plus row norms.
__global__ void proj_kernel(const float* __restrict__ X,
                            const float* __restrict__ w1t,
                            const float* __restrict__ bias,
                            float* __restrict__ outF,
                            __hip_bfloat16* __restrict__ outB,
                            float* __restrict__ norms) {
    __shared__ float w1s[D * H1];   // 64 KB, [d][o]
    int tid = threadIdx.x;
    const float4* s4 = (const float4*)w1t;
    float4* d4 = (float4*)w1s;
    #pragma unroll
    for (int i = tid; i < (D * H1) / 4; i += 256) d4[i] = s4[i];
    __syncthreads();

    int o  = tid >> 1;     // 0..127
    int kh = tid & 1;      // K half
    int r0 = blockIdx.x * QR;
    float bv = (bias != nullptr) ? bias[o] : 0.f;

    for (int r = 0; r < QR; ++r) {
        const float* xrow = X + (r0 + r) * D + kh * 64;
        const float* wcol = w1s + kh * 64 * H1 + o;
        float acc = 0.f;
        #pragma unroll 8
        for (int i = 0; i < 64; ++i)
            acc = fmaf(xrow[i], wcol[i * H1], acc);
        acc += __shfl_xor(acc, 1);
        if (kh == 0) {
            float v = acc + bv;
            if (outF) outF[(r0 + r) * H1 + o] = v;
            else      outB[(r0 + r) * H1 + o] = __float2bfloat16(v);
        }
    }
    if (tid < QR) {
        const float* xr = X + (r0 + tid) * D;
        float s = 0.f;
        for (int d = 0; d < D; ++d) s = fmaf(xr[d], xr[d], s);
        norms[r0 + tid] = s;
    }
}

// base[q][p] = max(qn+pn-2*q.p, 0). Tile 32q x 64p, 256 threads, grid 64*4.
#define BQ 32
#define BP 64
__global__ void base_kernel(const float* __restrict__ Q,
                            const float* __restrict__ P,
                            const float* __restrict__ qn,
                            const float* __restrict__ pn,
                            float* __restrict__ baseOut) {
    __shared__ float q_s[BQ][D + 1];
    __shared__ float p_s[BP][D + 1];
    int bq = blockIdx.x >> 2;
    int bp = blockIdx.x & 3;
    int q0 = bq * BQ, p0 = bp * BP;
    int tid = threadIdx.x;

    for (int i = tid; i < BQ * D; i += 256)
        q_s[i >> 7][i & 127] = Q[(q0 + (i >> 7)) * D + (i & 127)];
    for (int i = tid; i < BP * D; i += 256)
        p_s[i >> 7][i & 127] = P[(p0 + (i >> 7)) * D + (i & 127)];
    __syncthreads();

    int tp = tid & 15, tq = tid >> 4;
    int rq = tq * 2, cp = tp * 4;
    float acc[2][4] = {{0.f, 0.f, 0.f, 0.f}, {0.f, 0.f, 0.f, 0.f}};
    for (int d = 0; d < D; ++d) {
        float qa0 = q_s[rq][d],   qa1 = q_s[rq + 1][d];
        float pb0 = p_s[cp][d],   pb1 = p_s[cp + 1][d];
        float pb2 = p_s[cp + 2][d], pb3 = p_s[cp + 3][d];
        acc[0][0] = fmaf(qa0, pb0, acc[0][0]);
        acc[0][1] = fmaf(qa0, pb1, acc[0][1]);
        acc[0][2] = fmaf(qa0, pb2, acc[0][2]);
        acc[0][3] = fmaf(qa0, pb3, acc[0][3]);
        acc[1][0] = fmaf(qa1, pb0, acc[1][0]);
        acc[1][1] = fmaf(qa1, pb1, acc[1][1]);
        acc[1][2] = fmaf(qa1, pb2, acc[1][2]);
        acc[1][3] = fmaf(qa1, pb3, acc[1][3]);
    }
    #pragma unroll
    for (int j = 0; j < 2; ++j) {
        float qv = qn[q0 + rq + j];
        float4 v;
        v.x = fmaxf(qv + pn[p0 + cp + 0] - 2.f * acc[j][0], 0.f);
        v.y = fmaxf(qv + pn[p0 + cp + 1] - 2.f * acc[j][1], 0.f);
        v.z = fmaxf(qv + pn[p0 + cp + 2] - 2.f * acc[j][2], 0.f);
        v.w = fmaxf(qv + pn[p0 + cp + 3] - 2.f * acc[j][3], 0.f);
        *(float4*)(baseOut + (q0 + rq + j) * NP + p0 + cp) = v;
    }
}

// ---------------------------------------------------------------------------
// Main MFMA kernel. Per block: QB q-rows x all 256 p. 4 waves, wave w owns
// p in [64w, 64w+64). GEMM per q: C[o,p] = sum_h W2[o,h]*relu(qh[h]+ph[p,h]).
// A = W2 (M=64, preloaded in regs, reused all q), B built per (ks,n) from
// LDS ph (bf16, XOR-swizzled) + f32 qh. C/D: col(p)=lane&15, row(o)=g*4+reg.
// ---------------------------------------------------------------------------
__global__ void __launch_bounds__(256, 2)
main_kernel(const float* __restrict__ qhb,
            const __hip_bfloat16* __restrict__ phb,
            const float* __restrict__ W2,
            const float* __restrict__ b2,
            const float* __restrict__ w3,
            const float* __restrict__ b3,
            const float* __restrict__ baseM,
            float* __restrict__ out) {
    extern __shared__ char lds[];
    char*  ph_s = lds;                       // 65536 B swizzled [p][h] bf16
    float* qh_s = (float*)(lds + 65536);     // [QB][H1] f32

    int tid  = threadIdx.x;
    int lane = tid & 63;
    int w    = tid >> 6;       // wave 0..3 -> p base 64w
    int g    = lane >> 4;      // 0..3
    int lo   = lane & 15;
    int q0   = blockIdx.x * QB;

    // stage ph: 4096 chunks of 16 B, swizzled byte ^= (p&7)<<4
    #pragma unroll
    for (int it = 0; it < 16; ++it) {
        int c = it * 256 + tid;
        int p = c >> 4, hc = c & 15;
        uint4 v = *(const uint4*)((const char*)phb + p * 256 + hc * 16);
        int byte = (p * 256 + hc * 16) ^ ((p & 7) << 4);
        *(uint4*)(ph_s + byte) = v;
    }
    // stage qh rows for this block
    for (int i = tid; i < QB * (H1 / 4); i += 256)
        ((float4*)qh_s)[i] = ((const float4*)(qhb + (size_t)q0 * H1))[i];
    __syncthreads();

    // preload A-frags (W2) : Af[m][ks], row o = m*16+lo, k = ks*32+g*8+i
    short8 Af[4][4];
    #pragma unroll
    for (int m = 0; m < 4; ++m) {
        #pragma unroll
        for (int ks = 0; ks < 4; ++ks) {
            const float* src = W2 + (m * 16 + lo) * H1 + ks * 32 + g * 8;
            float4 a = *(const float4*)(src);
            float4 b = *(const float4*)(src + 4);
            short8 f;
            f[0] = f2bf(a.x); f[1] = f2bf(a.y); f[2] = f2bf(a.z); f[3] = f2bf(a.w);
            f[4] = f2bf(b.x); f[5] = f2bf(b.y); f[6] = f2bf(b.z); f[7] = f2bf(b.w);
            Af[m][ks] = f;
        }
    }
    // per-lane epilogue constants: o = m*16 + g*4 + reg
    float4 b2v[4], w3v[4];
    #pragma unroll
    for (int m = 0; m < 4; ++m) {
        b2v[m] = *(const float4*)(b2 + m * 16 + g * 4);
        w3v[m] = *(const float4*)(w3 + m * 16 + g * 4);
    }
    float b3v = b3[0];

    for (int qq = 0; qq < QB; ++qq) {
        f32x4 C[4][4];
        #pragma unroll
        for (int m = 0; m < 4; ++m)
            #pragma unroll
            for (int n = 0; n < 4; ++n)
                C[m][n] = (f32x4){0.f, 0.f, 0.f, 0.f};

        #pragma unroll
        for (int ks = 0; ks < 4; ++ks) {
            const float* qv = qh_s + qq * H1 + ks * 32 + g * 8;
            float4 qa = *(const float4*)(qv);
            float4 qb = *(const float4*)(qv + 4);
            short8 Bf[4];
            #pragma unroll
            for (int n = 0; n < 4; ++n) {
                int p = w * 64 + n * 16 + lo;
                int byte = (p * 256 + ks * 64 + g * 16) ^ ((p & 7) << 4);
                uint4 raw = *(const uint4*)(ph_s + byte);
                float t0 = fmaxf(bflo(raw.x) + qa.x, 0.f);
                float t1 = fmaxf(bfhi(raw.x) + qa.y, 0.f);
                float t2 = fmaxf(bflo(raw.y) + qa.z, 0.f);
                float t3 = fmaxf(bfhi(raw.y) + qa.w, 0.f);
                float t4 = fmaxf(bflo(raw.z) + qb.x, 0.f);
                float t5 = fmaxf(bfhi(raw.z) + qb.y, 0.f);
                float t6 = fmaxf(bflo(raw.w) + qb.z, 0.f);
                float t7 = fmaxf(bfhi(raw.w) + qb.w, 0.f);
                short8 f;
                f[0] = f2bf(t0); f[1] = f2bf(t1); f[2] = f2bf(t2); f[3] = f2bf(t3);
                f[4] = f2bf(t4); f[5] = f2bf(t5); f[6] = f2bf(t6); f[7] = f2bf(t7);
                Bf[n] = f;
            }
            #pragma unroll
            for (int m = 0; m < 4; ++m)
                #pragma unroll
                for (int n = 0; n < 4; ++n)
                    C[m][n] = __builtin_amdgcn_mfma_f32_16x16x32_bf16(
                        Af[m][ks], Bf[n], C[m][n], 0, 0, 0);
        }

        // epilogue: z[p] = sum_o relu(C[o,p]+b2[o])*w3[o]
        float zp[4];
        #pragma unroll
        for (int n = 0; n < 4; ++n) {
            float s = 0.f;
            #pragma unroll
            for (int m = 0; m < 4; ++m) {
                s = fmaf(fmaxf(C[m][n][0] + b2v[m].x, 0.f), w3v[m].x, s);
                s = fmaf(fmaxf(C[m][n][1] + b2v[m].y, 0.f), w3v[m].y, s);
                s = fmaf(fmaxf(C[m][n][2] + b2v[m].z, 0.f), w3v[m].z, s);
                s = fmaf(fmaxf(C[m][n][3] + b2v[m].w, 0.f), w3v[m].w, s);
            }
            s += __shfl_xor(s, 16);
            s += __shfl_xor(s, 32);
            zp[n] = s;
        }
        float z = (g == 0) ? zp[0] : (g == 1) ? zp[1] : (g == 2) ? zp[2] : zp[3];
        z += b3v;
        float sp = fmaxf(z, 0.f) + log1pf(expf(-fabsf(z)));   // stable softplus
        float alpha = 1.f + sp;
        float cw = 1.f / (1.f / alpha + 1e-8f);
        int p = w * 64 + lane;            // == w*64 + g*16 + lo
        int idx = (q0 + qq) * NP + p;
        out[idx] = baseM[idx] * cw;
    }
}

extern "C" void kernel_launch(void* const* d_in, const int* in_sizes, int n_in,
                              void* d_out, int out_size, void* d_ws, size_t ws_size,
                              hipStream_t stream) {
    const float* q  = (const float*)d_in[0];
    const float* pr = (const float*)d_in[1];
    const float* W1 = (const float*)d_in[2];
    const float* b1 = (const float*)d_in[3];
    const float* W2 = (const float*)d_in[4];
    const float* b2 = (const float*)d_in[5];
    const float* W3 = (const float*)d_in[6];
    const float* b3 = (const float*)d_in[7];
    float* out = (float*)d_out;
    float* ws  = (float*)d_ws;

    float* qhb  = ws + OFF_QHB;
    __hip_bfloat16* phb = (__hip_bfloat16*)(ws + OFF_PHB);
    float* w1qt = ws + OFF_W1QT;
    float* w1pt = ws + OFF_W1PT;
    float* qn   = ws + OFF_QN;
    float* pn   = ws + OFF_PN;
    float* baseM = ws + OFF_BASE;

    transpose_kernel<<<H1, 256, 0, stream>>>(W1, w1qt, w1pt);

    proj_kernel<<<NQ / QR, 256, 0, stream>>>(q, w1qt, b1, qhb, nullptr, qn);
    proj_kernel<<<NP / QR, 256, 0, stream>>>(pr, w1pt, nullptr, nullptr, phb, pn);

    base_kernel<<<(NQ / BQ) * (NP / BP), 256, 0, stream>>>(q, pr, qn, pn, baseM);

    int ldsBytes = 65536 + QB * H1 * (int)sizeof(float);
    main_kernel<<<NQ / QB, 256, ldsBytes, stream>>>(
        qhb, phb, W2, b2, W3, b3, baseM, out);
}

// Round 3
// 33.450 us; speedup vs baseline: 7.8317x; 2.7610x over previous
//
#include <hip/hip_runtime.h>
#include <hip/hip_bf16.h>
#include <hip/hip_fp16.h>

// Problem constants
#define D    128
#define NQ   2048
#define NP   256
#define H1   128
#define H2   64
#define QB   8     // q-rows per main block

typedef __attribute__((ext_vector_type(8))) _Float16 f16x8;
typedef __attribute__((ext_vector_type(4))) float    f32x4;

// ---------------------------------------------------------------------------
// Workspace layout (float units):
//   qh16  [NQ][H1] f16   q @ W1q^T + b1        off 0       (131072 f32 slots)
//   ph16  [NP][H1] f16   p @ W1p^T             off 131072  (16384)
//   qf16  [NQ][D]  f16   cast of q             off 147456  (131072)
//   pf16  [NP][D]  f16   cast of p             off 278528  (16384)
//   w2f   [H2][H1] f16   cast of W2            off 294912  (4096)
//   qn    [NQ]     f32                          off 299008  (2048)
//   pn    [NP]     f32                          off 301056  (256)
//   base  [NQ][NP] f32                          off 301312  (524288)
// ---------------------------------------------------------------------------
#define OFF_QH16 0
#define OFF_PH16 131072
#define OFF_QF16 147456
#define OFF_PF16 278528
#define OFF_W2F  294912
#define OFF_QN   299008
#define OFF_PN   301056
#define OFF_BASE 301312

static __device__ __forceinline__ f16x8 cvt8(float4 a, float4 b) {
    f16x8 f;
    f[0] = (_Float16)a.x; f[1] = (_Float16)a.y;
    f[2] = (_Float16)a.z; f[3] = (_Float16)a.w;
    f[4] = (_Float16)b.x; f[5] = (_Float16)b.y;
    f[6] = (_Float16)b.z; f[7] = (_Float16)b.w;
    return f;
}

// ---------------------------------------------------------------------------
// Prep: blocks 0..127 -> qh16 rows (16 each) + qf16 + qn
//       blocks 128..143 -> ph16 + pf16 + pn
//       block 144 -> W2 cast
// MFMA: M = 16 x-rows, N = o (wave w owns o in [32w,32w+32)), K = 128.
// ---------------------------------------------------------------------------
__global__ void __launch_bounds__(256)
prep_kernel(const float* __restrict__ q, const float* __restrict__ p,
            const float* __restrict__ W1, const float* __restrict__ b1,
            const float* __restrict__ W2,
            _Float16* __restrict__ qh16, _Float16* __restrict__ ph16,
            _Float16* __restrict__ qf16, _Float16* __restrict__ pf16,
            _Float16* __restrict__ w2f,
            float* __restrict__ qn, float* __restrict__ pn) {
    int bx = blockIdx.x, tid = threadIdx.x;
    if (bx == 144) {
        for (int i = tid; i < H2 * H1; i += 256)
            w2f[i] = (_Float16)W2[i];
        return;
    }
    bool isQ = bx < 128;
    const float* X = isQ ? q : p;
    int r0 = isQ ? bx * 16 : (bx - 128) * 16;
    int woff = isQ ? 0 : D;
    _Float16* hout = isQ ? qh16 : ph16;
    _Float16* xout = isQ ? qf16 : pf16;
    float* nrm = isQ ? qn : pn;

    int lane = tid & 63, w = tid >> 6;
    int lo = lane & 15, g = lane >> 4;
    int ob = w * 32;

    // A fragments from x rows (+ squared-norm partial)
    f16x8 A[4];
    float asq = 0.f;
    #pragma unroll
    for (int ks = 0; ks < 4; ++ks) {
        const float* src = X + (r0 + lo) * D + ks * 32 + g * 8;
        float4 a = *(const float4*)src, b = *(const float4*)(src + 4);
        asq += a.x * a.x + a.y * a.y + a.z * a.z + a.w * a.w
             + b.x * b.x + b.y * b.y + b.z * b.z + b.w * b.w;
        A[ks] = cvt8(a, b);
    }

    f32x4 C[2];
    #pragma unroll
    for (int n = 0; n < 2; ++n) C[n] = (f32x4){0.f, 0.f, 0.f, 0.f};
    #pragma unroll
    for (int n = 0; n < 2; ++n) {
        #pragma unroll
        for (int ks = 0; ks < 4; ++ks) {
            const float* src = W1 + (ob + n * 16 + lo) * (2 * D) + woff + ks * 32 + g * 8;
            float4 a = *(const float4*)src, b = *(const float4*)(src + 4);
            C[n] = __builtin_amdgcn_mfma_f32_16x16x32_f16(A[ks], cvt8(a, b), C[n], 0, 0, 0);
        }
    }
    // store h (row = r0 + g*4 + r, col = ob + n*16 + lo)
    #pragma unroll
    for (int n = 0; n < 2; ++n) {
        int o = ob + n * 16 + lo;
        float bv = isQ ? b1[o] : 0.f;
        #pragma unroll
        for (int r = 0; r < 4; ++r)
            hout[(r0 + g * 4 + r) * H1 + o] = (_Float16)(C[n][r] + bv);
    }
    // f16 copy of x + norms (wave 0 only; A is identical across waves)
    if (w == 0) {
        #pragma unroll
        for (int ks = 0; ks < 4; ++ks)
            *(f16x8*)(xout + (r0 + lo) * D + ks * 32 + g * 8) = A[ks];
        asq += __shfl_xor(asq, 16);
        asq += __shfl_xor(asq, 32);
        if (g == 0) nrm[r0 + lo] = asq;
    }
}

// ---------------------------------------------------------------------------
// Distance: base[q][p] = max(qn+pn-2*q.p, 0) via f16 MFMA.
// 128 blocks x 16 q-rows; wave w owns p in [64w, 64w+64).
// ---------------------------------------------------------------------------
__global__ void __launch_bounds__(256)
base_kernel(const _Float16* __restrict__ qf16, const _Float16* __restrict__ pf16,
            const float* __restrict__ qn, const float* __restrict__ pn,
            float* __restrict__ baseM) {
    int bx = blockIdx.x, tid = threadIdx.x;
    int lane = tid & 63, w = tid >> 6, lo = lane & 15, g = lane >> 4;
    int r0 = bx * 16;

    f16x8 A[4];
    #pragma unroll
    for (int ks = 0; ks < 4; ++ks)
        A[ks] = *(const f16x8*)(qf16 + (r0 + lo) * D + ks * 32 + g * 8);

    f32x4 C[4];
    #pragma unroll
    for (int n = 0; n < 4; ++n) C[n] = (f32x4){0.f, 0.f, 0.f, 0.f};
    #pragma unroll
    for (int n = 0; n < 4; ++n) {
        int pcol = w * 64 + n * 16 + lo;
        #pragma unroll
        for (int ks = 0; ks < 4; ++ks) {
            f16x8 B = *(const f16x8*)(pf16 + pcol * D + ks * 32 + g * 8);
            C[n] = __builtin_amdgcn_mfma_f32_16x16x32_f16(A[ks], B, C[n], 0, 0, 0);
        }
    }
    float4 qn4 = *(const float4*)(qn + r0 + g * 4);
    float qnv[4] = {qn4.x, qn4.y, qn4.z, qn4.w};
    #pragma unroll
    for (int n = 0; n < 4; ++n) {
        int pcol = w * 64 + n * 16 + lo;
        float pnv = pn[pcol];
        #pragma unroll
        for (int r = 0; r < 4; ++r)
            baseM[(r0 + g * 4 + r) * NP + pcol] =
                fmaxf(qnv[r] + pnv - 2.f * C[n][r], 0.f);
    }
}

// ---------------------------------------------------------------------------
// Main: per block QB=8 q-rows x 256 p. Wave w owns p in [64w,64w+64).
// C[o,p] = sum_h W2[o,h] * relu(qh[h] + ph[p,h])  via f16 MFMA.
// ph fragments + W2 fragments register-resident; qh broadcast from 2KB LDS.
// B-build: 4 v_pk_add_f16 + 4 v_pk_max_f16 per fragment.
// ---------------------------------------------------------------------------
__global__ void __launch_bounds__(256, 2)
main_kernel(const _Float16* __restrict__ qh16, const _Float16* __restrict__ ph16,
            const _Float16* __restrict__ w2f,
            const float* __restrict__ b2, const float* __restrict__ w3,
            const float* __restrict__ b3,
            const float* __restrict__ baseM, float* __restrict__ out) {
    __shared__ _Float16 qh_s[QB * H1];   // 2 KB
    int tid = threadIdx.x, lane = tid & 63, w = tid >> 6;
    int lo = lane & 15, g = lane >> 4;
    int q0 = blockIdx.x * QB;

    if (tid < (QB * H1) / 8)
        ((uint4*)qh_s)[tid] = ((const uint4*)(qh16 + q0 * H1))[tid];
    __syncthreads();

    // ph fragments [n][ks], register-resident (64 VGPR)
    f16x8 P[4][4];
    #pragma unroll
    for (int n = 0; n < 4; ++n)
        #pragma unroll
        for (int ks = 0; ks < 4; ++ks)
            P[n][ks] = *(const f16x8*)(ph16 + (w * 64 + n * 16 + lo) * H1 + ks * 32 + g * 8);

    // W2 fragments [m][ks] (64 VGPR)
    f16x8 Af[4][4];
    #pragma unroll
    for (int m = 0; m < 4; ++m)
        #pragma unroll
        for (int ks = 0; ks < 4; ++ks)
            Af[m][ks] = *(const f16x8*)(w2f + (m * 16 + lo) * H1 + ks * 32 + g * 8);

    float4 b2v[4], w3v[4];
    #pragma unroll
    for (int m = 0; m < 4; ++m) {
        b2v[m] = *(const float4*)(b2 + m * 16 + g * 4);
        w3v[m] = *(const float4*)(w3 + m * 16 + g * 4);
    }
    float b3v = b3[0];
    const f16x8 zz = {};

    for (int qq = 0; qq < QB; ++qq) {
        f16x8 qk[4];
        #pragma unroll
        for (int ks = 0; ks < 4; ++ks)
            qk[ks] = *(const f16x8*)(qh_s + qq * H1 + ks * 32 + g * 8);

        float zp[4];
        #pragma unroll
        for (int hh = 0; hh < 2; ++hh) {          // n-halves keep C at 32 VGPR
            f32x4 C[4][2];
            #pragma unroll
            for (int m = 0; m < 4; ++m) {
                C[m][0] = (f32x4){0.f, 0.f, 0.f, 0.f};
                C[m][1] = (f32x4){0.f, 0.f, 0.f, 0.f};
            }
            #pragma unroll
            for (int ks = 0; ks < 4; ++ks) {
                f16x8 B0 = __builtin_elementwise_max(P[2 * hh + 0][ks] + qk[ks], zz);
                f16x8 B1 = __builtin_elementwise_max(P[2 * hh + 1][ks] + qk[ks], zz);
                #pragma unroll
                for (int m = 0; m < 4; ++m) {
                    C[m][0] = __builtin_amdgcn_mfma_f32_16x16x32_f16(Af[m][ks], B0, C[m][0], 0, 0, 0);
                    C[m][1] = __builtin_amdgcn_mfma_f32_16x16x32_f16(Af[m][ks], B1, C[m][1], 0, 0, 0);
                }
            }
            #pragma unroll
            for (int n2 = 0; n2 < 2; ++n2) {
                float s = 0.f;
                #pragma unroll
                for (int m = 0; m < 4; ++m) {
                    s = fmaf(fmaxf(C[m][n2][0] + b2v[m].x, 0.f), w3v[m].x, s);
                    s = fmaf(fmaxf(C[m][n2][1] + b2v[m].y, 0.f), w3v[m].y, s);
                    s = fmaf(fmaxf(C[m][n2][2] + b2v[m].z, 0.f), w3v[m].z, s);
                    s = fmaf(fmaxf(C[m][n2][3] + b2v[m].w, 0.f), w3v[m].w, s);
                }
                s += __shfl_xor(s, 16);
                s += __shfl_xor(s, 32);
                zp[2 * hh + n2] = s;
            }
        }
        float z = (g == 0) ? zp[0] : (g == 1) ? zp[1] : (g == 2) ? zp[2] : zp[3];
        z += b3v;
        float sp = fmaxf(z, 0.f) + log1pf(expf(-fabsf(z)));   // stable softplus
        float alpha = 1.f + sp;
        float cw = 1.f / (1.f / alpha + 1e-8f);
        int idx = (q0 + qq) * NP + w * 64 + lane;
        out[idx] = baseM[idx] * cw;
    }
}

extern "C" void kernel_launch(void* const* d_in, const int* in_sizes, int n_in,
                              void* d_out, int out_size, void* d_ws, size_t ws_size,
                              hipStream_t stream) {
    const float* q  = (const float*)d_in[0];
    const float* pr = (const float*)d_in[1];
    const float* W1 = (const float*)d_in[2];
    const float* b1 = (const float*)d_in[3];
    const float* W2 = (const float*)d_in[4];
    const float* b2 = (const float*)d_in[5];
    const float* W3 = (const float*)d_in[6];
    const float* b3 = (const float*)d_in[7];
    float* out = (float*)d_out;
    float* ws  = (float*)d_ws;

    _Float16* qh16 = (_Float16*)(ws + OFF_QH16);
    _Float16* ph16 = (_Float16*)(ws + OFF_PH16);
    _Float16* qf16 = (_Float16*)(ws + OFF_QF16);
    _Float16* pf16 = (_Float16*)(ws + OFF_PF16);
    _Float16* w2f  = (_Float16*)(ws + OFF_W2F);
    float* qn    = ws + OFF_QN;
    float* pn    = ws + OFF_PN;
    float* baseM = ws + OFF_BASE;

    prep_kernel<<<145, 256, 0, stream>>>(q, pr, W1, b1, W2,
                                         qh16, ph16, qf16, pf16, w2f, qn, pn);
    base_kernel<<<NQ / 16, 256, 0, stream>>>(qf16, pf16, qn, pn, baseM);
    main_kernel<<<NQ / QB, 256, 0, stream>>>(qh16, ph16, w2f, b2, W3, b3, baseM, out);
}